// Round 3
// baseline (82.926 us; speedup 1.0000x reference)
//
#include <hip/hip_runtime.h>
#include <hip/hip_bf16.h>

// MeanPooling: out[b,e,d] = (sum_l map[b,e,l]*doc[b,l,d]) / lens[b,e]
// B=16, E=256, L=4096 (=K), D=512. fp32 in/out, bf16 MFMA inside.
//
// R3: prefetch state moved into LDS so regalloc can't collapse it (R2 failure).
//  - 512 blocks x 4 waves, split-K x4 (wave K=1024), 64x64 tile/wave.
//  - A (emap, k-contiguous): direct global->reg, 1-iter single-buffer pipeline.
//  - B (doc, k-major): per-wave-private LDS ping-pong tile [32][64] fp32,
//    XOR-swizzled (cg ^= 2*((k>>3)&3)) -> 2-way bank access (free).
//    Staged via 256B-contiguous dwordx4 loads. No barriers in k-loop.
//  - LDS = 4 waves x 2 x 8KB = 64KB exactly; aliased as reduction buffer.

#define NB 16
#define NE 256
#define NL 4096
#define ND 512
#define KSPLIT 4
#define KPW (NL / KSPLIT)   // 1024 per wave
#define NT (KPW / 32)       // 32 k-tiles of 32 per wave

using f32x4  = __attribute__((ext_vector_type(4))) float;
using bf16x8 = __attribute__((ext_vector_type(8))) short;

static __device__ __forceinline__ short f2bf(float x) {
  __bf16 h = (__bf16)x;   // hardware RNE convert
  return __builtin_bit_cast(short, h);
}

// ---- pipeline building blocks (macros so all indices stay compile-time) ----

// B global tile T -> 8 f32x4 regs (lane: k=4i+gp, cols 4*c4..+3; 256B segments)
#define LOADB(DST, T)                                                          \
  do {                                                                         \
    const float* pb_ = bg + (size_t)(T) * 32 * ND;                             \
    _Pragma("unroll") for (int i_ = 0; i_ < 8; ++i_)                           \
        DST[i_] = *reinterpret_cast<const f32x4*>(pb_ + (size_t)i_ * 4 * ND);  \
  } while (0)

// A global tile T -> 8 f32x4 regs (row=16m+l15, k = T*32 + 8g .. +7)
#define LOADA(DST, T)                                                          \
  do {                                                                         \
    size_t ka_ = (size_t)(T) * 32;                                             \
    _Pragma("unroll") for (int m_ = 0; m_ < 4; ++m_) {                         \
      const float* pa_ = aPtr[m_] + ka_;                                       \
      DST[2 * m_]     = *reinterpret_cast<const f32x4*>(pa_);                  \
      DST[2 * m_ + 1] = *reinterpret_cast<const f32x4*>(pa_ + 4);              \
    }                                                                          \
  } while (0)

// Ar regs (fp32) -> 4 bf16x8 A fragments
#define CVTA(FR, AR)                                                           \
  _Pragma("unroll") for (int m_ = 0; m_ < 4; ++m_)                             \
      _Pragma("unroll") for (int j_ = 0; j_ < 4; ++j_) {                       \
    FR[m_][j_]     = f2bf(AR[2 * m_][j_]);                                     \
    FR[m_][4 + j_] = f2bf(AR[2 * m_ + 1][j_]);                                 \
  }

// Br regs -> LDS buf (swizzled b128 writes)
#define WRB(BR, BUF)                                                           \
  _Pragma("unroll") for (int i_ = 0; i_ < 8; ++i_)                             \
      *reinterpret_cast<f32x4*>(&myT[(BUF) * 2048 + wroff[i_]]) = BR[i_];

// read 4 B frags from LDS buf, cvt, 16 MFMA into acc
#define COMPUTE(BUF)                                                           \
  do {                                                                         \
    bf16x8 bfr_[4];                                                            \
    _Pragma("unroll") for (int n_ = 0; n_ < 4; ++n_) {                         \
      float tb_[8];                                                            \
      _Pragma("unroll") for (int j_ = 0; j_ < 8; ++j_)                         \
          tb_[j_] = myT[(BUF) * 2048 + rdn[n_] + j_ * 64];                     \
      _Pragma("unroll") for (int j_ = 0; j_ < 8; ++j_)                         \
          bfr_[n_][j_] = f2bf(tb_[j_]);                                        \
    }                                                                          \
    _Pragma("unroll") for (int m_ = 0; m_ < 4; ++m_)                           \
        _Pragma("unroll") for (int n_ = 0; n_ < 4; ++n_)                       \
            acc[m_][n_] = __builtin_amdgcn_mfma_f32_16x16x32_bf16(             \
                afrag[m_], bfr_[n_], acc[m_][n_], 0, 0, 0);                    \
  } while (0)

__global__ __launch_bounds__(256, 2) void mp_gemm(const float* __restrict__ doc,
                                                  const float* __restrict__ emap,
                                                  const float* __restrict__ lens,
                                                  float* __restrict__ out) {
  // 64KB: per-wave ping-pong B tiles [4 waves][2 bufs][2048 dwords];
  // aliased as [4][4096] fp32 reduction buffer after the k-loop.
  __shared__ float smem[4 * 2 * 2048];

  int bid = (int)blockIdx.x;
  // XCD-chunk swizzle: XCD x gets logical blocks [64x, 64x+63]
  int logical = (bid & 7) * 64 + (bid >> 3);
  int b  = logical >> 5;        // 16 batches (2 per XCD chunk)
  int et = (logical >> 3) & 3;  // 4 e-tiles of 64 rows
  int dt = logical & 7;         // 8 d-tiles of 64 cols

  int tid  = (int)threadIdx.x;
  int w    = tid >> 6;          // wave = K-split index
  int lane = tid & 63;
  int l15  = lane & 15;
  int g    = lane >> 4;         // k-group 0..3 (frag) ; also gp for staging
  float* myT = smem + w * 4096;

  // --- B staging addressing (swizzle: cg' = cg ^ (2*((k>>3)&3)) ) ---
  // write: lane stages k = 4i + g, cols 4*l15..+3
  int wroff[8];
#pragma unroll
  for (int i = 0; i < 8; ++i)
    wroff[i] = (4 * i + g) * 64 + ((l15 ^ (2 * (i >> 1))) << 2);
  // read: frag n needs (k = 8g + j, col = 16n + l15)
  int rdn[4];
#pragma unroll
  for (int n = 0; n < 4; ++n)
    rdn[n] = g * 512 + (((4 * n + (l15 >> 2)) ^ (2 * g)) << 2) + (l15 & 3);

  const float* Ab = emap + (size_t)(b * NE + et * 64) * NL;  // [64][L]
  const float* Bt = doc + (size_t)b * NL * ND + dt * 64 + (size_t)w * KPW * ND;
  const float* bg = Bt + (size_t)g * ND + l15 * 4;  // lane's staging base

  const float* aPtr[4];
#pragma unroll
  for (int m = 0; m < 4; ++m)
    aPtr[m] = Ab + (size_t)(16 * m + l15) * NL + w * KPW + 8 * g;

  f32x4 acc[4][4] = {};  // rows 4g..4g+3, col l15 per frag
  f32x4 Ar[8], Br[8];
  bf16x8 afrag[4];

  // prologue: invariant at loop entry -> Ar=A(t), Br=B(t+1), buf0=tile t
  LOADB(Br, 0);
  LOADA(Ar, 0);
  WRB(Br, 0);
  LOADB(Br, 1);

#pragma unroll 1
  for (int t = 0; t < NT; t += 2) {
    int t1 = t + 1;
    int t2 = t + 2 < NT ? t + 2 : NT - 1;  // clamped prefetch (tail-safe)
    int t3 = t + 3 < NT ? t + 3 : NT - 1;
    // even: tile t from buf0
    CVTA(afrag, Ar);
    LOADA(Ar, t1);
    WRB(Br, 1);       // tile t+1 -> buf1
    LOADB(Br, t2);
    COMPUTE(0);
    // odd: tile t+1 from buf1
    CVTA(afrag, Ar);
    LOADA(Ar, t2);
    WRB(Br, 0);       // tile t+2 -> buf0
    LOADB(Br, t3);
    COMPUTE(1);
  }

  // fp32 partials -> own LDS region (wave-private, no barrier needed yet).
  // C/D frag: row = 16m + 4g + i, col = 16n + l15.
#pragma unroll
  for (int m = 0; m < 4; ++m)
#pragma unroll
    for (int n = 0; n < 4; ++n)
#pragma unroll
      for (int i = 0; i < 4; ++i)
        myT[(16 * m + 4 * g + i) * 64 + 16 * n + l15] = acc[m][n][i];

  __syncthreads();

  // Cross-wave reduce + divide + store: 256 threads x 16 passes over 64x64.
  const float* lb = lens + b * NE + et * 64;
  float* ob = out + (size_t)(b * NE + et * 64) * ND + dt * 64;
#pragma unroll
  for (int p = 0; p < 16; ++p) {
    int idx = p * 256 + tid;
    float s = smem[idx] + smem[4096 + idx] + smem[8192 + idx] + smem[12288 + idx];
    int row = idx >> 6;
    int col = idx & 63;
    ob[(size_t)row * ND + col] = s / lb[row];
  }
}

extern "C" void kernel_launch(void* const* d_in, const int* in_sizes, int n_in,
                              void* d_out, int out_size, void* d_ws, size_t ws_size,
                              hipStream_t stream) {
  const float* doc  = (const float*)d_in[0];  // (B, L, D)
  const float* emap = (const float*)d_in[1];  // (B, E, L)
  const float* lens = (const float*)d_in[2];  // (B, E)
  float* out = (float*)d_out;                 // (B, E, D)
  hipLaunchKernelGGL(mp_gemm, dim3(512), dim3(256), 0, stream, doc, emap, lens, out);
}